// Round 1
// baseline (619.298 us; speedup 1.0000x reference)
//
#include <hip/hip_runtime.h>
#include <hip/hip_bf16.h>

#define B_ 8
#define N_ 2048
#define D_ 128

typedef __bf16 bf16_t;
typedef __bf16 v8bf __attribute__((ext_vector_type(8)));
typedef float  v4f  __attribute__((ext_vector_type(4)));

// ---------------------------------------------------------------------------
// Kernel 1: h = x@W_w + W_b ; g = h@A_w.  One block per (b,n) row.
// Stores hb (bf16 row-major), gb (bf16 row-major), hbT (bf16 [b][d][n]).
// ---------------------------------------------------------------------------
__global__ __launch_bounds__(128) void k_hg(
    const float* __restrict__ x, const float* __restrict__ Ww,
    const float* __restrict__ Wb, const float* __restrict__ Aw,
    bf16_t* __restrict__ hb, bf16_t* __restrict__ gb, bf16_t* __restrict__ hbT)
{
    int row = blockIdx.x;          // b*N + n
    int b = row >> 11;
    int n = row & (N_ - 1);
    int j = threadIdx.x;
    __shared__ float xs[D_];
    __shared__ float hs[D_];
    xs[j] = x[(size_t)row * D_ + j];
    __syncthreads();
    float acc = Wb[j];
#pragma unroll 8
    for (int k = 0; k < D_; ++k) acc += xs[k] * Ww[k * D_ + j];
    hs[j] = acc;
    hb[(size_t)row * D_ + j] = (bf16_t)acc;
    hbT[(size_t)b * D_ * N_ + (size_t)j * N_ + n] = (bf16_t)acc;
    __syncthreads();
    float g = 0.f;
#pragma unroll 8
    for (int k = 0; k < D_; ++k) g += hs[k] * Aw[k * D_ + j];
    gb[(size_t)row * D_ + j] = (bf16_t)g;
}

// ---------------------------------------------------------------------------
// Kernel 2: colsum[b][m] = sum_n adj[b][n][m] * exp(e[b][n][m])
// e tile (16n x 16m) via MFMA:  E = G_n H_m^T + H_n G_m^T
// grid: b(8) x mblk(32, 64 cols each) x nchunk(8, 256 rows each) = 2048 blocks
// block: 4 waves; wave w owns 16 columns (mblk*64 + w*16).
// ---------------------------------------------------------------------------
__global__ __launch_bounds__(256) void k_colsum(
    const bf16_t* __restrict__ hb, const bf16_t* __restrict__ gb,
    const float* __restrict__ adj, float* __restrict__ colsum)
{
    int bid = blockIdx.x;
    int b = bid >> 8;
    int rem = bid & 255;
    int mblk = rem >> 3;
    int nchunk = rem & 7;
    int wave = threadIdx.x >> 6;
    int lane = threadIdx.x & 63;
    int q = lane >> 4;
    int c = lane & 15;
    int mbase = mblk * 64 + wave * 16;
    const size_t hgoff = (size_t)b * N_ * D_;

    // B-operand fragments for this wave's 16 columns (rows mbase.. of H, G)
    v8bf bh[4], bg[4];
#pragma unroll
    for (int kc = 0; kc < 4; ++kc) {
        size_t off = hgoff + (size_t)(mbase + c) * D_ + kc * 32 + q * 8;
        bh[kc] = *(const v8bf*)(hb + off);
        bg[kc] = *(const v8bf*)(gb + off);
    }

    float lsum = 0.f;
    int n0 = nchunk * 256;
    const float* adjb = adj + (size_t)b * N_ * N_;
    for (int ns = 0; ns < 16; ++ns) {
        int nb = n0 + ns * 16;
        v4f acc = {0.f, 0.f, 0.f, 0.f};
#pragma unroll
        for (int kc = 0; kc < 4; ++kc) {
            size_t off = hgoff + (size_t)(nb + c) * D_ + kc * 32 + q * 8;
            v8bf ag = *(const v8bf*)(gb + off);
            v8bf ah = *(const v8bf*)(hb + off);
            acc = __builtin_amdgcn_mfma_f32_16x16x32_bf16(ag, bh[kc], acc, 0, 0, 0);
            acc = __builtin_amdgcn_mfma_f32_16x16x32_bf16(ah, bg[kc], acc, 0, 0, 0);
        }
#pragma unroll
        for (int r = 0; r < 4; ++r) {
            int nn = nb + q * 4 + r;
            float a = adjb[(size_t)nn * N_ + mbase + c];
            lsum += (a > 0.f) ? __expf(acc[r]) : 0.f;
        }
    }
    // reduce over the 4 quads (lanes sharing the same column c)
    lsum += __shfl_xor(lsum, 16);
    lsum += __shfl_xor(lsum, 32);
    if (lane < 16) atomicAdd(&colsum[b * N_ + mbase + lane], lsum);
}

// ---------------------------------------------------------------------------
// Kernel 3: inv = colsum > 0 ? 1/colsum : 0   (dead-column guard)
// ---------------------------------------------------------------------------
__global__ __launch_bounds__(256) void k_inv(
    const float* __restrict__ cs, float* __restrict__ inv)
{
    int i = blockIdx.x * 256 + threadIdx.x;
    float s = cs[i];
    inv[i] = (s > 0.f) ? 1.f / s : 0.f;
}

// ---------------------------------------------------------------------------
// Kernel 4: h_prime = relu( P @ H ), P[n,m] = adj*exp(e)*inv[m]; then gate+out.
// grid: b(8) x nblk(32, 64 rows each) = 256 blocks, 512 threads (8 waves).
// waves 0-3: n-subtiles 0-3, m in [0,1024); waves 4-7: same subtiles, m in
// [1024,2048). LDS combine, then fused relu/gate/output epilogue.
// ---------------------------------------------------------------------------
__global__ __launch_bounds__(512) void k_out(
    const bf16_t* __restrict__ hb, const bf16_t* __restrict__ gb,
    const bf16_t* __restrict__ hbT, const float* __restrict__ adj,
    const float* __restrict__ inv, const float* __restrict__ x,
    const float* __restrict__ gw, const float* __restrict__ gbias,
    float* __restrict__ out)
{
    int bid = blockIdx.x;
    int b = bid >> 5;
    int nblk = bid & 31;
    int tid = threadIdx.x;
    int wave = tid >> 6;
    int lane = tid & 63;
    int q = lane >> 4;
    int c = lane & 15;
    int wn = wave & 3;       // n-subtile
    int half = wave >> 2;    // m-half
    int nbase = nblk * 64 + wn * 16;
    const size_t hgoff = (size_t)b * N_ * D_;

    __shared__ float pbuf[8][16 * 36];   // per-wave P transform buffer
    __shared__ float hp[64][132];        // h_prime combine buffer

    // A-operand fragments for E: this wave's 16 n-rows of G and H (fixed)
    v8bf ag[4], ah[4];
#pragma unroll
    for (int kc = 0; kc < 4; ++kc) {
        size_t off = hgoff + (size_t)(nbase + c) * D_ + kc * 32 + q * 8;
        ag[kc] = *(const v8bf*)(gb + off);
        ah[kc] = *(const v8bf*)(hb + off);
    }

    v4f hpacc[8];
#pragma unroll
    for (int dt = 0; dt < 8; ++dt) hpacc[dt] = (v4f){0.f, 0.f, 0.f, 0.f};

    const float* adjb = adj + (size_t)b * N_ * N_;
    const bf16_t* hTb = hbT + (size_t)b * D_ * N_;
    float* pw = pbuf[wave];

    for (int ch = 0; ch < 32; ++ch) {
        int mchunk = half * 1024 + ch * 32;
#pragma unroll
        for (int t = 0; t < 2; ++t) {
            int mt = mchunk + t * 16;
            v4f e = {0.f, 0.f, 0.f, 0.f};
#pragma unroll
            for (int kc = 0; kc < 4; ++kc) {
                size_t off = hgoff + (size_t)(mt + c) * D_ + kc * 32 + q * 8;
                v8bf bh = *(const v8bf*)(hb + off);
                v8bf bg = *(const v8bf*)(gb + off);
                e = __builtin_amdgcn_mfma_f32_16x16x32_bf16(ag[kc], bh, e, 0, 0, 0);
                e = __builtin_amdgcn_mfma_f32_16x16x32_bf16(ah[kc], bg, e, 0, 0, 0);
            }
            float iv = inv[b * N_ + mt + c];
#pragma unroll
            for (int r = 0; r < 4; ++r) {
                int nn = nbase + q * 4 + r;
                float a = adjb[(size_t)nn * N_ + mt + c];
                float w = (a > 0.f) ? __expf(e[r]) * iv : 0.f;
                pw[(q * 4 + r) * 36 + t * 16 + c] = w;
            }
        }
        __syncthreads();
        // C-layout -> A-layout read-back (16B aligned, stride-36 padding)
        v4f p0 = *(const v4f*)&pw[c * 36 + q * 8];
        v4f p1 = *(const v4f*)&pw[c * 36 + q * 8 + 4];
        v8bf pf;
#pragma unroll
        for (int j2 = 0; j2 < 4; ++j2) {
            pf[j2]     = (bf16_t)p0[j2];
            pf[j2 + 4] = (bf16_t)p1[j2];
        }
#pragma unroll
        for (int dt = 0; dt < 8; ++dt) {
            const bf16_t* src = hTb + (size_t)(dt * 16 + c) * N_ + mchunk + q * 8;
            v8bf bt = *(const v8bf*)src;
            hpacc[dt] = __builtin_amdgcn_mfma_f32_16x16x32_bf16(pf, bt, hpacc[dt], 0, 0, 0);
        }
        __syncthreads();
    }

    // combine the two m-halves in LDS
    if (half == 0) {
#pragma unroll
        for (int dt = 0; dt < 8; ++dt)
#pragma unroll
            for (int r = 0; r < 4; ++r)
                hp[wn * 16 + q * 4 + r][dt * 16 + c] = hpacc[dt][r];
    }
    __syncthreads();
    if (half == 1) {
#pragma unroll
        for (int dt = 0; dt < 8; ++dt)
#pragma unroll
            for (int r = 0; r < 4; ++r)
                hp[wn * 16 + q * 4 + r][dt * 16 + c] += hpacc[dt][r];
    }
    __syncthreads();

    // epilogue: coeff = sigmoid([x, relu(hp)] @ gw + gb); out = lerp
    int row = tid >> 3;
    int seg = tid & 7;
    int n = nblk * 64 + row;
    const float* xrow = x + ((size_t)b * N_ + n) * D_;
    float partial = 0.f;
#pragma unroll
    for (int jj = 0; jj < 16; ++jj) {
        int d = seg * 16 + jj;
        float xv = xrow[d];
        float hv = fmaxf(hp[row][d], 0.f);
        partial += xv * gw[d] + hv * gw[D_ + d];
    }
    partial += __shfl_xor(partial, 1);
    partial += __shfl_xor(partial, 2);
    partial += __shfl_xor(partial, 4);
    float coeff = 1.f / (1.f + __expf(-(partial + gbias[0])));
    float* orow = out + ((size_t)b * N_ + n) * D_;
#pragma unroll
    for (int jj = 0; jj < 16; ++jj) {
        int d = seg * 16 + jj;
        float xv = xrow[d];
        float hv = fmaxf(hp[row][d], 0.f);
        orow[d] = coeff * xv + (1.f - coeff) * hv;
    }
}

// ---------------------------------------------------------------------------
extern "C" void kernel_launch(void* const* d_in, const int* in_sizes, int n_in,
                              void* d_out, int out_size, void* d_ws, size_t ws_size,
                              hipStream_t stream)
{
    const float* x     = (const float*)d_in[0];
    const float* adj   = (const float*)d_in[1];
    const float* Ww    = (const float*)d_in[2];
    const float* Wb    = (const float*)d_in[3];
    const float* Aw    = (const float*)d_in[4];
    const float* gw    = (const float*)d_in[5];
    const float* gbias = (const float*)d_in[6];
    float* out = (float*)d_out;

    char* ws = (char*)d_ws;
    bf16_t* hb     = (bf16_t*)(ws);                          // 4 MB
    bf16_t* gb     = (bf16_t*)(ws + (4 << 20));              // 4 MB
    bf16_t* hbT    = (bf16_t*)(ws + (8 << 20));              // 4 MB
    float*  colsum = (float*)(ws + (12 << 20));              // 64 KB
    float*  inv    = (float*)(ws + (12 << 20) + (64 << 10)); // 64 KB

    hipMemsetAsync(colsum, 0, B_ * N_ * sizeof(float), stream);
    k_hg<<<B_ * N_, 128, 0, stream>>>(x, Ww, Wb, Aw, hb, gb, hbT);
    k_colsum<<<2048, 256, 0, stream>>>(hb, gb, adj, colsum);
    k_inv<<<B_ * N_ / 256, 256, 0, stream>>>(colsum, inv);
    k_out<<<256, 512, 0, stream>>>(hb, gb, hbT, adj, inv, x, gw, gbias, out);
}